// Round 4
// baseline (1062.563 us; speedup 1.0000x reference)
//
#include <hip/hip_runtime.h>
#include <math.h>

#define NROWS   32768
#define CDIM    256
#define KCODES  1024
#define ZQ_ELEMS 8388608   // 32*256*32*32

typedef short  bshort8 __attribute__((ext_vector_type(8)));   // 8 bf16 (4 VGPRs)
typedef float  f32x4   __attribute__((ext_vector_type(4)));

// ---- ws layout (floats) ----
#define ESQ_OFF   0          // 1024
#define ZSQH_OFF  1024       // 2*32768 (zsq half-sums)
#define TB_OFF    66560      // 4*32768 best
#define TS_OFF    197632     // 4*32768 second
#define TI_OFF    328704     // 4*32768 best idx (int)
#define IDX_OFF   459776     // 32768 (int)
#define LIST_OFF  492544     // 32768 (int)
#define CNT_OFF   525312     // 1 int
#define ACC_OFF   525313     // 1 float
#define BHI_OFF   525328     // 131072 uints (16B aligned): B hi-fragments

// d_out scratch: A hi-fragments (16 MB) in the z_q region, overwritten by gather.

#define MARGIN_ABS 8.0e-4f   // >= 2*err_max(bf16-hi dot) + rounding slop; see analysis

__device__ __forceinline__ ushort f2bf(float f) {
    union { float f; uint u; } v; v.f = f;
    uint lsb = (v.u >> 16) & 1u;
    return (ushort)((v.u + 0x7fffu + lsb) >> 16);
}

// ================= prep: e_sq (numpy pairwise semantics) =================
__global__ __launch_bounds__(256) void esq_kernel(const float* __restrict__ cb,
                                                  float* __restrict__ esq) {
    int k = blockIdx.x * 256 + threadIdx.x;
    if (k >= KCODES) return;
    const float* p = cb + (size_t)k * CDIM;
    float half_[2];
    for (int h = 0; h < 2; ++h) {
        const float* q = p + h * 128;
        float r8[8];
#pragma unroll
        for (int j = 0; j < 8; ++j) { float v = q[j]; r8[j] = __fmul_rn(v, v); }
        for (int i = 8; i < 128; i += 8) {
#pragma unroll
            for (int j = 0; j < 8; ++j) {
                float v = q[i + j];
                r8[j] = __fadd_rn(r8[j], __fmul_rn(v, v));
            }
        }
        half_[h] = __fadd_rn(__fadd_rn(__fadd_rn(r8[0], r8[1]), __fadd_rn(r8[2], r8[3])),
                             __fadd_rn(__fadd_rn(r8[4], r8[5]), __fadd_rn(r8[6], r8[7])));
    }
    esq[k] = __fadd_rn(half_[0], half_[1]);
}

// ================= prep: pack codebook into B hi-fragments =================
// F = (ct*8+ks)*64+lane ; elem j -> cb[ct*16+(lane&15)][ks*32+(lane>>4)*8+j]
__global__ __launch_bounds__(256) void packB_kernel(const float* __restrict__ cb,
                                                    uint* __restrict__ Bhi) {
    int F = blockIdx.x * 256 + threadIdx.x;   // 0..32767
    int ct = F >> 9, ks = (F >> 6) & 7, ln = F & 63;
    int code = ct * 16 + (ln & 15);
    int k0 = ks * 32 + (ln >> 4) * 8;
    const float* p = cb + (size_t)code * CDIM + k0;
    float4 va = *(const float4*)p;
    float4 vb = *(const float4*)(p + 4);
    float v[8] = {va.x, va.y, va.z, va.w, vb.x, vb.y, vb.z, vb.w};
    uint h[4];
#pragma unroll
    for (int d = 0; d < 4; ++d)
        h[d] = (uint)f2bf(v[2*d]) | ((uint)f2bf(v[2*d+1]) << 16);
    *(uint4*)(Bhi + (size_t)F * 4) = make_uint4(h[0], h[1], h[2], h[3]);
}

// ================= prep: pack z into A hi-fragments + zsq half-sums =================
// grid 256 = 128 rowgroups(256 rows) x 2 k-halves(128 dims).
__global__ __launch_bounds__(256) void packA_kernel(const float* __restrict__ z,
                                                    uint* __restrict__ Ahi,
                                                    float* __restrict__ zsqh) {
    __shared__ float zt[32][257];
    const int tid = threadIdx.x;
    const int rg  = blockIdx.x >> 1;
    const int h   = blockIdx.x & 1;
    const int b   = rg >> 2;
    const int hw0 = (rg & 3) * 256;

    float r8[8];
    const int rt0 = rg * 16;

    for (int kcl = 0; kcl < 4; ++kcl) {
        const int ks = h * 4 + kcl;
        __syncthreads();
        for (int kk = 0; kk < 32; ++kk)
            zt[kk][tid] = z[((size_t)b * 256 + ks * 32 + kk) * 1024 + hw0 + tid];
        __syncthreads();

#pragma unroll
        for (int g = 0; g < 4; ++g)
#pragma unroll
            for (int j = 0; j < 8; ++j) {
                float v = zt[g * 8 + j][tid];
                float sq = __fmul_rn(v, v);
                r8[j] = (kcl == 0 && g == 0) ? sq : __fadd_rn(r8[j], sq);
            }

#pragma unroll
        for (int it = 0; it < 4; ++it) {
            int slot = it * 256 + tid;
            int rt_l = slot >> 6, lane = slot & 63;
            int row_l = rt_l * 16 + (lane & 15);
            int k0_l  = (lane >> 4) * 8;
            uint hh[4];
#pragma unroll
            for (int d = 0; d < 4; ++d) {
                float v0 = zt[k0_l + 2*d][row_l];
                float v1 = zt[k0_l + 2*d + 1][row_l];
                hh[d] = (uint)f2bf(v0) | ((uint)f2bf(v1) << 16);
            }
            size_t F = ((size_t)(rt0 + rt_l) * 8 + ks) * 64 + lane;
            *(uint4*)(Ahi + F * 4) = make_uint4(hh[0], hh[1], hh[2], hh[3]);
        }
    }
    float hs = __fadd_rn(__fadd_rn(__fadd_rn(r8[0], r8[1]), __fadd_rn(r8[2], r8[3])),
                         __fadd_rn(__fadd_rn(r8[4], r8[5]), __fadd_rn(r8[6], r8[7])));
    zsqh[h * NROWS + rg * 256 + tid] = hs;
}

// ================= main: hi-only MFMA + per-row top-2 =================
// grid 512 = 256 rowgroups(128 rows) x 2 col-halves(512 cols); 4 waves 2x2.
__global__ __launch_bounds__(256, 2) void main_mfma(const uint* __restrict__ Ahi,
                                                    const uint* __restrict__ Bhi,
                                                    const float* __restrict__ esq,
                                                    const float* __restrict__ zsqh,
                                                    float* __restrict__ tb, float* __restrict__ ts,
                                                    int* __restrict__ ti) {
    __shared__ uint a_h[2][8][64][4];
    __shared__ uint b_h[2][8][64][4];
    __shared__ float esq_s[512];
    __shared__ float zsq_s[128];

    const int tid  = threadIdx.x;
    const int rg   = blockIdx.x >> 1;
    const int half = blockIdx.x & 1;
    const int w    = tid >> 6;
    const int lane = tid & 63;
    const int wr   = w >> 1;
    const int wc   = w & 1;

    {
        float2 e2 = *(const float2*)(esq + half * 512 + tid * 2);
        esq_s[tid * 2] = e2.x; esq_s[tid * 2 + 1] = e2.y;
        if (tid < 128) {
            int row = rg * 128 + tid;
            zsq_s[tid] = __fadd_rn(zsqh[row], zsqh[NROWS + row]);
        }
    }

#define GLDS(SRC, DST) __builtin_amdgcn_global_load_lds(                          \
        (const __attribute__((address_space(1))) void*)(SRC),                     \
        (__attribute__((address_space(3))) void*)(DST), 16, 0, 0)

    auto stage = [&](int t) {
        int ctg = t >> 3, ks = t & 7, buf = t & 1;
#pragma unroll
        for (int r = 0; r < 2; ++r) {
            int rtl = w * 2 + r;
            size_t FA = (((size_t)rg * 8 + rtl) * 8 + ks) * 64 + lane;
            GLDS(Ahi + FA * 4, &a_h[buf][rtl][0][0]);
            size_t FB = (((size_t)half * 32 + ctg * 8 + rtl) * 8 + ks) * 64 + lane;
            GLDS(Bhi + FB * 4, &b_h[buf][rtl][0][0]);
        }
    };

    float best[16], sec[16]; int bidx[16];
#pragma unroll
    for (int s = 0; s < 16; ++s) { best[s] = INFINITY; sec[s] = INFINITY; bidx[s] = 0; }

    f32x4 acc[4][4];

    stage(0);
    __syncthreads();

    for (int t = 0; t < 32; ++t) {
        const int buf = t & 1;
        if ((t & 7) == 0) {
#pragma unroll
            for (int rt = 0; rt < 4; ++rt)
#pragma unroll
                for (int c = 0; c < 4; ++c) acc[rt][c] = (f32x4){0.f, 0.f, 0.f, 0.f};
        }
        if (t < 31) stage(t + 1);

        {
            bshort8 bh[4];
#pragma unroll
            for (int c = 0; c < 4; ++c)
                bh[c] = *(const bshort8*)&b_h[buf][wc * 4 + c][lane][0];
#pragma unroll
            for (int rt = 0; rt < 4; ++rt) {
                bshort8 ah = *(const bshort8*)&a_h[buf][wr * 4 + rt][lane][0];
#pragma unroll
                for (int c = 0; c < 4; ++c)
                    acc[rt][c] = __builtin_amdgcn_mfma_f32_16x16x32_bf16(ah, bh[c], acc[rt][c], 0, 0, 0);
            }
        }

        if ((t & 7) == 7) {
            const int ctg = t >> 3;
            const int g = lane >> 4, cl = lane & 15;
#pragma unroll
            for (int rt = 0; rt < 4; ++rt)
#pragma unroll
                for (int c = 0; c < 4; ++c) {
                    int col_l = ctg * 128 + (wc * 4 + c) * 16 + cl;
                    float es = esq_s[col_l];
                    int code = half * 512 + col_l;
                    f32x4 a = acc[rt][c];
#pragma unroll
                    for (int reg = 0; reg < 4; ++reg) {
                        int rowl = wr * 64 + rt * 16 + g * 4 + reg;
                        float t1 = __fadd_rn(zsq_s[rowl], es);
                        float dd = __fadd_rn(t1, __fmul_rn(-2.0f, a[reg]));
                        int s = rt * 4 + reg;
                        if (dd < best[s]) { sec[s] = best[s]; best[s] = dd; bidx[s] = code; }
                        else if (dd < sec[s]) sec[s] = dd;
                    }
                }
        }
        __syncthreads();
    }

#pragma unroll
    for (int mk = 1; mk <= 8; mk <<= 1) {
#pragma unroll
        for (int s = 0; s < 16; ++s) {
            float ob = __shfl_xor(best[s], mk, 64);
            float os = __shfl_xor(sec[s],  mk, 64);
            int   oi = __shfl_xor(bidx[s], mk, 64);
            float mx = fmaxf(best[s], ob);
            sec[s] = fminf(fminf(sec[s], os), mx);
            if (ob < best[s] || (ob == best[s] && oi < bidx[s])) { best[s] = ob; bidx[s] = oi; }
        }
    }
    if ((lane & 15) == 0) {
        const int g = lane >> 4;
        const int q = half * 2 + wc;
#pragma unroll
        for (int s = 0; s < 16; ++s) {
            int rt = s >> 2, reg = s & 3;
            int row = rg * 128 + wr * 64 + rt * 16 + g * 4 + reg;
            size_t o = (size_t)q * NROWS + row;
            tb[o] = best[s]; ts[o] = sec[s]; ti[o] = bidx[s];
        }
    }
#undef GLDS
}

// ================= finalize: merge 4 quarters, flag near-ties =================
__global__ __launch_bounds__(256) void finalize_kernel(const float* __restrict__ tb,
                                                       const float* __restrict__ ts,
                                                       const int* __restrict__ ti,
                                                       float* __restrict__ oidxf,
                                                       int* __restrict__ idx_i,
                                                       int* __restrict__ list,
                                                       int* __restrict__ count) {
    int row = blockIdx.x * 256 + threadIdx.x;
    float b = INFINITY, s = INFINITY; int bi = 0;
#pragma unroll
    for (int q = 0; q < 4; ++q) {
        float v = tb[(size_t)q * NROWS + row];
        int  vi = ti[(size_t)q * NROWS + row];
        if (v < b || (v == b && vi < bi)) { s = b; b = v; bi = vi; }
        else s = fminf(s, v);
        s = fminf(s, ts[(size_t)q * NROWS + row]);
    }
    if (s <= b + MARGIN_ABS) {
        int p = atomicAdd(count, 1);
        list[p] = row;
    } else {
        oidxf[row] = (float)bi;
        idx_i[row] = bi;
    }
}

// ================= rescan: exact fp32 chain, 1 row per block =================
__global__ __launch_bounds__(256) void rescan_kernel(const float* __restrict__ z,
                                                     const float* __restrict__ cb,
                                                     const float* __restrict__ esq,
                                                     const float* __restrict__ zsqh,
                                                     const int* __restrict__ list,
                                                     const int* __restrict__ count,
                                                     float* __restrict__ oidxf,
                                                     int* __restrict__ idx_i) {
    __shared__ float zrow[256];
    __shared__ float rb[256];
    __shared__ int   ri[256];
    const int tid = threadIdx.x;
    const int n = count[0];
    for (int i = blockIdx.x; i < n; i += gridDim.x) {
        const int row = list[i];
        __syncthreads();
        zrow[tid] = z[((size_t)(row >> 10) * 256 + tid) * 1024 + (row & 1023)];
        __syncthreads();
        const float zs = __fadd_rn(zsqh[row], zsqh[NROWS + row]);
        const float* cp = cb + (size_t)tid * 256;
        float a0 = 0.f, a1 = 0.f, a2 = 0.f, a3 = 0.f;
#pragma unroll 2
        for (int k = 0; k < 256; k += 4) {
            float4 c0 = *(const float4*)(cp + k);
            float4 c1 = *(const float4*)(cp + 65536 + k);
            float4 c2 = *(const float4*)(cp + 131072 + k);
            float4 c3 = *(const float4*)(cp + 196608 + k);
            float z0 = zrow[k], z1 = zrow[k+1], z2 = zrow[k+2], z3 = zrow[k+3];
            a0 = fmaf(z0, c0.x, a0); a0 = fmaf(z1, c0.y, a0); a0 = fmaf(z2, c0.z, a0); a0 = fmaf(z3, c0.w, a0);
            a1 = fmaf(z0, c1.x, a1); a1 = fmaf(z1, c1.y, a1); a1 = fmaf(z2, c1.z, a1); a1 = fmaf(z3, c1.w, a1);
            a2 = fmaf(z0, c2.x, a2); a2 = fmaf(z1, c2.y, a2); a2 = fmaf(z2, c2.z, a2); a2 = fmaf(z3, c2.w, a2);
            a3 = fmaf(z0, c3.x, a3); a3 = fmaf(z1, c3.y, a3); a3 = fmaf(z2, c3.z, a3); a3 = fmaf(z3, c3.w, a3);
        }
        float av[4] = {a0, a1, a2, a3};
        float bv = INFINITY; int bi = 0;
#pragma unroll
        for (int q = 0; q < 4; ++q) {
            int code = q * 256 + tid;
            float dd = __fadd_rn(__fadd_rn(zs, esq[code]), __fmul_rn(-2.0f, av[q]));
            if (dd < bv) { bv = dd; bi = code; }
        }
        rb[tid] = bv; ri[tid] = bi;
        __syncthreads();
        for (int s = 128; s > 0; s >>= 1) {
            if (tid < s) {
                if (rb[tid + s] < rb[tid] ||
                    (rb[tid + s] == rb[tid] && ri[tid + s] < ri[tid])) {
                    rb[tid] = rb[tid + s]; ri[tid] = ri[tid + s];
                }
            }
            __syncthreads();
        }
        if (tid == 0) { oidxf[row] = (float)ri[0]; idx_i[row] = ri[0]; }
    }
}

// ================= gather z_q + loss =================
__global__ __launch_bounds__(256) void gather_kernel(const float* __restrict__ z,
                                                     const float* __restrict__ cb,
                                                     const int* __restrict__ idx_i,
                                                     float* __restrict__ out0,
                                                     float* __restrict__ accum) {
    int tid   = threadIdx.x;
    int blk   = blockIdx.x;
    int b     = blk >> 5;
    int chunk = (blk >> 3) & 3;
    int cgrp  = blk & 7;
    int hw = chunk * 256 + tid;
    int n  = b * 1024 + hw;
    int code = idx_i[n];
    const float* cp = cb + (size_t)code * CDIM + cgrp * 32;
    float lsum = 0.0f;
    size_t base = (size_t)b * 262144 + hw + (size_t)(cgrp * 32) * 1024;
#pragma unroll
    for (int cc = 0; cc < 8; ++cc) {
        float4 q4 = *(const float4*)(cp + cc * 4);
        float qv[4] = {q4.x, q4.y, q4.z, q4.w};
#pragma unroll
        for (int u = 0; u < 4; ++u) {
            size_t off = base + (size_t)(cc * 4 + u) * 1024;
            float zv = z[off];
            out0[off] = qv[u];
            float dfr = zv - qv[u];
            lsum = fmaf(dfr, dfr, lsum);
        }
    }
#pragma unroll
    for (int mm = 32; mm >= 1; mm >>= 1) lsum += __shfl_down(lsum, mm, 64);
    __shared__ float red[4];
    int wv = tid >> 6, ln = tid & 63;
    if (ln == 0) red[wv] = lsum;
    __syncthreads();
    if (tid == 0) atomicAdd(accum, (red[0] + red[1]) + (red[2] + red[3]));
}

__global__ void finalize_loss(const float* __restrict__ accum, float* __restrict__ out_loss) {
    out_loss[0] = accum[0] * (1.25f / 8388608.0f);
}

extern "C" void kernel_launch(void* const* d_in, const int* in_sizes, int n_in,
                              void* d_out, int out_size, void* d_ws, size_t ws_size,
                              hipStream_t stream) {
    const float* z  = (const float*)d_in[0];   // [32,256,32,32]
    const float* cb = (const float*)d_in[1];   // [1024,256]

    float* ws   = (float*)d_ws;
    float* esq  = ws + ESQ_OFF;
    float* zsqh = ws + ZSQH_OFF;
    float* tb   = ws + TB_OFF;
    float* ts   = ws + TS_OFF;
    int*   ti   = (int*)(ws + TI_OFF);
    int*   idx_i = (int*)(ws + IDX_OFF);
    int*   list = (int*)(ws + LIST_OFF);
    int*   cnt  = (int*)(ws + CNT_OFF);
    float* accum = ws + ACC_OFF;
    uint*  Bhi  = (uint*)(ws + BHI_OFF);

    float* out0     = (float*)d_out;
    float* out_loss = out0 + ZQ_ELEMS;
    float* out_idxf = out0 + ZQ_ELEMS + 1;

    // A hi-fragments (16 MB) live in the z_q region of d_out (consumed before gather overwrites)
    uint* Ahi = (uint*)out0;

    hipMemsetAsync(cnt, 0, 8, stream);  // count + accum

    esq_kernel  <<<4,   256, 0, stream>>>(cb, esq);
    packB_kernel<<<128, 256, 0, stream>>>(cb, Bhi);
    packA_kernel<<<256, 256, 0, stream>>>(z, Ahi, zsqh);
    main_mfma   <<<512, 256, 0, stream>>>(Ahi, Bhi, esq, zsqh, tb, ts, ti);
    finalize_kernel<<<128, 256, 0, stream>>>(tb, ts, ti, out_idxf, idx_i, list, cnt);
    rescan_kernel<<<1024, 256, 0, stream>>>(z, cb, esq, zsqh, list, cnt, out_idxf, idx_i);
    gather_kernel<<<1024, 256, 0, stream>>>(z, cb, idx_i, out0, accum);
    finalize_loss<<<1, 1, 0, stream>>>(accum, out_loss);
}

// Round 5
// 214.888 us; speedup vs baseline: 4.9447x; 4.9447x over previous
//
#include <hip/hip_runtime.h>
#include <math.h>

#define NROWS   32768
#define CDIM    256
#define KCODES  1024
#define ZQ_ELEMS 8388608   // 32*256*32*32

typedef short  bshort8 __attribute__((ext_vector_type(8)));   // 8 bf16 (4 VGPRs)
typedef float  f32x4   __attribute__((ext_vector_type(4)));

// ---- ws layout (floats) ----
#define ESQ_OFF   0          // 1024
#define ZSQH_OFF  1024       // 2*32768 (zsq half-sums)
#define TB_OFF    66560      // 4*32768 best   (reused as cbT[256][1024] after finalize)
#define TS_OFF    197632     // 4*32768 second (second half of cbT)
#define TI_OFF    328704     // 4*32768 best idx (int)
#define IDX_OFF   459776     // 32768 (int)
#define LIST_OFF  492544     // 32768 (int)
#define CNT_OFF   525312     // 1 int
#define ACC_OFF   525313     // 1 float
#define BHI_OFF   525328     // 131072 uints (16B aligned)
#define BLO_OFF   656400     // 131072 uints

// d_out scratch: A hi/lo fragments (32 MB) fill the z_q region, overwritten by gather.

#define MARGIN_ABS 1.0e-4f   // tie-safe: ulp(dist~256)=3.05e-5 + 2*dist_err(~2e-5) < 1e-4

__device__ __forceinline__ ushort f2bf(float f) {
    union { float f; uint u; } v; v.f = f;
    uint lsb = (v.u >> 16) & 1u;
    return (ushort)((v.u + 0x7fffu + lsb) >> 16);
}
__device__ __forceinline__ float bf2f(ushort b) {
    union { uint u; float f; } v; v.u = ((uint)b) << 16;
    return v.f;
}

// ================= prep: e_sq (numpy pairwise semantics) =================
__global__ __launch_bounds__(256) void esq_kernel(const float* __restrict__ cb,
                                                  float* __restrict__ esq) {
    int k = blockIdx.x * 256 + threadIdx.x;
    if (k >= KCODES) return;
    const float* p = cb + (size_t)k * CDIM;
    float half_[2];
    for (int h = 0; h < 2; ++h) {
        const float* q = p + h * 128;
        float r8[8];
#pragma unroll
        for (int j = 0; j < 8; ++j) { float v = q[j]; r8[j] = __fmul_rn(v, v); }
        for (int i = 8; i < 128; i += 8) {
#pragma unroll
            for (int j = 0; j < 8; ++j) {
                float v = q[i + j];
                r8[j] = __fadd_rn(r8[j], __fmul_rn(v, v));
            }
        }
        half_[h] = __fadd_rn(__fadd_rn(__fadd_rn(r8[0], r8[1]), __fadd_rn(r8[2], r8[3])),
                             __fadd_rn(__fadd_rn(r8[4], r8[5]), __fadd_rn(r8[6], r8[7])));
    }
    esq[k] = __fadd_rn(half_[0], half_[1]);
}

// ================= prep: pack codebook into B-fragments (bf16 hi/lo) =================
__global__ __launch_bounds__(256) void packB_kernel(const float* __restrict__ cb,
                                                    uint* __restrict__ Bhi, uint* __restrict__ Blo) {
    int F = blockIdx.x * 256 + threadIdx.x;   // 0..32767
    int ct = F >> 9, ks = (F >> 6) & 7, ln = F & 63;
    int code = ct * 16 + (ln & 15);
    int k0 = ks * 32 + (ln >> 4) * 8;
    const float* p = cb + (size_t)code * CDIM + k0;
    float4 va = *(const float4*)p;
    float4 vb = *(const float4*)(p + 4);
    float v[8] = {va.x, va.y, va.z, va.w, vb.x, vb.y, vb.z, vb.w};
    uint h[4], l[4];
#pragma unroll
    for (int d = 0; d < 4; ++d) {
        ushort h0 = f2bf(v[2*d]);   float r0 = v[2*d]   - bf2f(h0);
        ushort h1 = f2bf(v[2*d+1]); float r1 = v[2*d+1] - bf2f(h1);
        h[d] = (uint)h0 | ((uint)h1 << 16);
        l[d] = (uint)f2bf(r0) | ((uint)f2bf(r1) << 16);
    }
    *(uint4*)(Bhi + (size_t)F * 4) = make_uint4(h[0], h[1], h[2], h[3]);
    *(uint4*)(Blo + (size_t)F * 4) = make_uint4(l[0], l[1], l[2], l[3]);
}

// ================= prep: pack z into A-fragments (hi/lo) + zsq half-sums =================
__global__ __launch_bounds__(256) void packA_kernel(const float* __restrict__ z,
                                                    uint* __restrict__ Ahi, uint* __restrict__ Alo,
                                                    float* __restrict__ zsqh) {
    __shared__ float zt[32][257];
    const int tid = threadIdx.x;
    const int rg  = blockIdx.x >> 1;
    const int h   = blockIdx.x & 1;
    const int b   = rg >> 2;
    const int hw0 = (rg & 3) * 256;

    float r8[8];
    const int rt0 = rg * 16;

    for (int kcl = 0; kcl < 4; ++kcl) {
        const int ks = h * 4 + kcl;
        __syncthreads();
        for (int kk = 0; kk < 32; ++kk)
            zt[kk][tid] = z[((size_t)b * 256 + ks * 32 + kk) * 1024 + hw0 + tid];
        __syncthreads();

#pragma unroll
        for (int g = 0; g < 4; ++g)
#pragma unroll
            for (int j = 0; j < 8; ++j) {
                float v = zt[g * 8 + j][tid];
                float sq = __fmul_rn(v, v);
                r8[j] = (kcl == 0 && g == 0) ? sq : __fadd_rn(r8[j], sq);
            }

#pragma unroll
        for (int it = 0; it < 4; ++it) {
            int slot = it * 256 + tid;
            int rt_l = slot >> 6, lane = slot & 63;
            int row_l = rt_l * 16 + (lane & 15);
            int k0_l  = (lane >> 4) * 8;
            uint hh[4], ll[4];
#pragma unroll
            for (int d = 0; d < 4; ++d) {
                float v0 = zt[k0_l + 2*d][row_l];
                float v1 = zt[k0_l + 2*d + 1][row_l];
                ushort h0 = f2bf(v0); float q0 = v0 - bf2f(h0);
                ushort h1 = f2bf(v1); float q1 = v1 - bf2f(h1);
                hh[d] = (uint)h0 | ((uint)h1 << 16);
                ll[d] = (uint)f2bf(q0) | ((uint)f2bf(q1) << 16);
            }
            size_t F = ((size_t)(rt0 + rt_l) * 8 + ks) * 64 + lane;
            *(uint4*)(Ahi + F * 4) = make_uint4(hh[0], hh[1], hh[2], hh[3]);
            *(uint4*)(Alo + F * 4) = make_uint4(ll[0], ll[1], ll[2], ll[3]);
        }
    }
    float hs = __fadd_rn(__fadd_rn(__fadd_rn(r8[0], r8[1]), __fadd_rn(r8[2], r8[3])),
                         __fadd_rn(__fadd_rn(r8[4], r8[5]), __fadd_rn(r8[6], r8[7])));
    zsqh[h * NROWS + rg * 256 + tid] = hs;
}

// ================= main: hi/lo MFMA + per-row top-2 =================
__global__ __launch_bounds__(256, 2) void main_mfma(const uint* __restrict__ Ahi,
                                                    const uint* __restrict__ Alo,
                                                    const uint* __restrict__ Bhi,
                                                    const uint* __restrict__ Blo,
                                                    const float* __restrict__ esq,
                                                    const float* __restrict__ zsqh,
                                                    float* __restrict__ tb, float* __restrict__ ts,
                                                    int* __restrict__ ti) {
    __shared__ uint a_hi[2][8][64][4];
    __shared__ uint a_lo[2][8][64][4];
    __shared__ uint b_hi[2][8][64][4];
    __shared__ uint b_lo[2][8][64][4];
    __shared__ float esq_s[512];
    __shared__ float zsq_s[128];

    const int tid  = threadIdx.x;
    const int rg   = blockIdx.x >> 1;
    const int half = blockIdx.x & 1;
    const int w    = tid >> 6;
    const int lane = tid & 63;
    const int wr   = w >> 1;
    const int wc   = w & 1;

    {
        float2 e2 = *(const float2*)(esq + half * 512 + tid * 2);
        esq_s[tid * 2] = e2.x; esq_s[tid * 2 + 1] = e2.y;
        if (tid < 128) {
            int row = rg * 128 + tid;
            zsq_s[tid] = __fadd_rn(zsqh[row], zsqh[NROWS + row]);
        }
    }

#define GLDS(SRC, DST) __builtin_amdgcn_global_load_lds(                          \
        (const __attribute__((address_space(1))) void*)(SRC),                     \
        (__attribute__((address_space(3))) void*)(DST), 16, 0, 0)

    auto stage = [&](int t) {
        int ctg = t >> 3, ks = t & 7, buf = t & 1;
#pragma unroll
        for (int r = 0; r < 2; ++r) {
            int rtl = w * 2 + r;
            size_t FA = (((size_t)rg * 8 + rtl) * 8 + ks) * 64 + lane;
            GLDS(Ahi + FA * 4, &a_hi[buf][rtl][0][0]);
            GLDS(Alo + FA * 4, &a_lo[buf][rtl][0][0]);
            size_t FB = (((size_t)half * 32 + ctg * 8 + rtl) * 8 + ks) * 64 + lane;
            GLDS(Bhi + FB * 4, &b_hi[buf][rtl][0][0]);
            GLDS(Blo + FB * 4, &b_lo[buf][rtl][0][0]);
        }
    };

    float best[16], sec[16]; int bidx[16];
#pragma unroll
    for (int s = 0; s < 16; ++s) { best[s] = INFINITY; sec[s] = INFINITY; bidx[s] = 0; }

    f32x4 acc[4][4];

    stage(0);
    __syncthreads();

    for (int t = 0; t < 32; ++t) {
        const int buf = t & 1;
        if ((t & 7) == 0) {
#pragma unroll
            for (int rt = 0; rt < 4; ++rt)
#pragma unroll
                for (int c = 0; c < 4; ++c) acc[rt][c] = (f32x4){0.f, 0.f, 0.f, 0.f};
        }
        if (t < 31) stage(t + 1);

        {
            bshort8 bh[4], bl[4];
#pragma unroll
            for (int c = 0; c < 4; ++c) {
                bh[c] = *(const bshort8*)&b_hi[buf][wc * 4 + c][lane][0];
                bl[c] = *(const bshort8*)&b_lo[buf][wc * 4 + c][lane][0];
            }
#pragma unroll
            for (int rt = 0; rt < 4; ++rt) {
                bshort8 ah = *(const bshort8*)&a_hi[buf][wr * 4 + rt][lane][0];
                bshort8 al = *(const bshort8*)&a_lo[buf][wr * 4 + rt][lane][0];
#pragma unroll
                for (int c = 0; c < 4; ++c) {
                    acc[rt][c] = __builtin_amdgcn_mfma_f32_16x16x32_bf16(al, bh[c], acc[rt][c], 0, 0, 0);
                    acc[rt][c] = __builtin_amdgcn_mfma_f32_16x16x32_bf16(ah, bl[c], acc[rt][c], 0, 0, 0);
                    acc[rt][c] = __builtin_amdgcn_mfma_f32_16x16x32_bf16(ah, bh[c], acc[rt][c], 0, 0, 0);
                }
            }
        }

        if ((t & 7) == 7) {
            const int ctg = t >> 3;
            const int g = lane >> 4, cl = lane & 15;
#pragma unroll
            for (int rt = 0; rt < 4; ++rt)
#pragma unroll
                for (int c = 0; c < 4; ++c) {
                    int col_l = ctg * 128 + (wc * 4 + c) * 16 + cl;
                    float es = esq_s[col_l];
                    int code = half * 512 + col_l;
                    f32x4 a = acc[rt][c];
#pragma unroll
                    for (int reg = 0; reg < 4; ++reg) {
                        int rowl = wr * 64 + rt * 16 + g * 4 + reg;
                        float t1 = __fadd_rn(zsq_s[rowl], es);
                        float dd = __fadd_rn(t1, __fmul_rn(-2.0f, a[reg]));
                        int s = rt * 4 + reg;
                        if (dd < best[s]) { sec[s] = best[s]; best[s] = dd; bidx[s] = code; }
                        else if (dd < sec[s]) sec[s] = dd;
                    }
                }
        }
        __syncthreads();
    }

#pragma unroll
    for (int mk = 1; mk <= 8; mk <<= 1) {
#pragma unroll
        for (int s = 0; s < 16; ++s) {
            float ob = __shfl_xor(best[s], mk, 64);
            float os = __shfl_xor(sec[s],  mk, 64);
            int   oi = __shfl_xor(bidx[s], mk, 64);
            float mx = fmaxf(best[s], ob);
            sec[s] = fminf(fminf(sec[s], os), mx);
            if (ob < best[s] || (ob == best[s] && oi < bidx[s])) { best[s] = ob; bidx[s] = oi; }
        }
    }
    if ((lane & 15) == 0) {
        const int g = lane >> 4;
        const int q = half * 2 + wc;
#pragma unroll
        for (int s = 0; s < 16; ++s) {
            int rt = s >> 2, reg = s & 3;
            int row = rg * 128 + wr * 64 + rt * 16 + g * 4 + reg;
            size_t o = (size_t)q * NROWS + row;
            tb[o] = best[s]; ts[o] = sec[s]; ti[o] = bidx[s];
        }
    }
#undef GLDS
}

// ================= finalize: merge 4 quarters, flag near-ties =================
__global__ __launch_bounds__(256) void finalize_kernel(const float* __restrict__ tb,
                                                       const float* __restrict__ ts,
                                                       const int* __restrict__ ti,
                                                       float* __restrict__ oidxf,
                                                       int* __restrict__ idx_i,
                                                       int* __restrict__ list,
                                                       int* __restrict__ count) {
    int row = blockIdx.x * 256 + threadIdx.x;
    float b = INFINITY, s = INFINITY; int bi = 0;
#pragma unroll
    for (int q = 0; q < 4; ++q) {
        float v = tb[(size_t)q * NROWS + row];
        int  vi = ti[(size_t)q * NROWS + row];
        if (v < b || (v == b && vi < bi)) { s = b; b = v; bi = vi; }
        else s = fminf(s, v);
        s = fminf(s, ts[(size_t)q * NROWS + row]);
    }
    if (s <= b + MARGIN_ABS) {
        int p = atomicAdd(count, 1);
        list[p] = row;
    } else {
        oidxf[row] = (float)bi;
        idx_i[row] = bi;
    }
}

// ================= transpose codebook (runs after finalize, into dead tb/ts region) ====
__global__ __launch_bounds__(256) void transpose_cb_kernel(const float* __restrict__ cb,
                                                           float* __restrict__ cbT) {
    int tid = blockIdx.x * 256 + threadIdx.x;   // tid = k*1024 + code
    int k = tid >> 10;
    int code = tid & 1023;
    cbT[tid] = cb[code * CDIM + k];
}

// ================= rescan: exact fp32 chain; 16 rows/block, 4 rows/wave =================
__global__ __launch_bounds__(256) void rescan_kernel(const float* __restrict__ z,
                                                     const float* __restrict__ cbT,
                                                     const float* __restrict__ esq,
                                                     const float* __restrict__ zsqh,
                                                     const int* __restrict__ list,
                                                     const int* __restrict__ count,
                                                     float* __restrict__ oidxf,
                                                     int* __restrict__ idx_i) {
    __shared__ float ct_lds[8][1024];   // 32 KB: k-subtile x all codes
    __shared__ float z_lds[16][256];    // 16 KB: row slot x k
    __shared__ float esq_lds[1024];     // 4 KB
    const int tid = threadIdx.x, lane = tid & 63, w = tid >> 6;
    const int n = count[0];
#pragma unroll
    for (int i = 0; i < 4; ++i) esq_lds[i * 256 + tid] = esq[i * 256 + tid];

    for (int base = blockIdx.x * 16; base < n; base += gridDim.x * 16) {
        __syncthreads();   // previous iteration's reads done
        // stage 16 z-rows (scattered; coalesced within a row is impossible)
        for (int i = 0; i < 16; ++i) {
            int gi = base + i;
            int row = list[gi < n ? gi : n - 1];
            z_lds[i][tid] = z[((size_t)(row >> 10) * 256 + tid) * 1024 + (row & 1023)];
        }

        float acc[4][16];
#pragma unroll
        for (int r = 0; r < 4; ++r)
#pragma unroll
            for (int j = 0; j < 16; ++j) acc[r][j] = 0.0f;

        for (int kt = 0; kt < 32; ++kt) {
            __syncthreads();
            // stage cbT k-subtile: 8 x 1024 floats, fully coalesced
#pragma unroll
            for (int u = 0; u < 8; ++u) {
                float4 v = *(const float4*)(cbT + (size_t)(kt * 8 + u) * 1024 + tid * 4);
                *(float4*)&ct_lds[u][tid * 4] = v;
            }
            __syncthreads();
#pragma unroll
            for (int k8 = 0; k8 < 8; ++k8) {
                float4 c[4];
#pragma unroll
                for (int j = 0; j < 4; ++j)
                    c[j] = *(const float4*)&ct_lds[k8][lane * 16 + j * 4];
#pragma unroll
                for (int r = 0; r < 4; ++r) {
                    float zv = z_lds[w * 4 + r][kt * 8 + k8];
                    acc[r][0]  = fmaf(zv, c[0].x, acc[r][0]);
                    acc[r][1]  = fmaf(zv, c[0].y, acc[r][1]);
                    acc[r][2]  = fmaf(zv, c[0].z, acc[r][2]);
                    acc[r][3]  = fmaf(zv, c[0].w, acc[r][3]);
                    acc[r][4]  = fmaf(zv, c[1].x, acc[r][4]);
                    acc[r][5]  = fmaf(zv, c[1].y, acc[r][5]);
                    acc[r][6]  = fmaf(zv, c[1].z, acc[r][6]);
                    acc[r][7]  = fmaf(zv, c[1].w, acc[r][7]);
                    acc[r][8]  = fmaf(zv, c[2].x, acc[r][8]);
                    acc[r][9]  = fmaf(zv, c[2].y, acc[r][9]);
                    acc[r][10] = fmaf(zv, c[2].z, acc[r][10]);
                    acc[r][11] = fmaf(zv, c[2].w, acc[r][11]);
                    acc[r][12] = fmaf(zv, c[3].x, acc[r][12]);
                    acc[r][13] = fmaf(zv, c[3].y, acc[r][13]);
                    acc[r][14] = fmaf(zv, c[3].z, acc[r][14]);
                    acc[r][15] = fmaf(zv, c[3].w, acc[r][15]);
                }
            }
        }

        // epilogue: distances + wave argmin reduce (lanes own ascending code blocks)
#pragma unroll
        for (int r = 0; r < 4; ++r) {
            int slot = w * 4 + r;
            int gi = base + slot;
            int row = list[gi < n ? gi : n - 1];
            float zs = __fadd_rn(zsqh[row], zsqh[NROWS + row]);
            float bv = INFINITY; int bi = 0;
#pragma unroll
            for (int j = 0; j < 16; ++j) {
                int code = lane * 16 + j;
                float dd = __fadd_rn(__fadd_rn(zs, esq_lds[code]), __fmul_rn(-2.0f, acc[r][j]));
                if (dd < bv) { bv = dd; bi = code; }
            }
#pragma unroll
            for (int mk = 1; mk <= 32; mk <<= 1) {
                float ob = __shfl_xor(bv, mk, 64);
                int   oi = __shfl_xor(bi, mk, 64);
                if (ob < bv || (ob == bv && oi < bi)) { bv = ob; bi = oi; }
            }
            if (lane == 0 && gi < n) { oidxf[row] = (float)bi; idx_i[row] = bi; }
        }
    }
}

// ================= gather z_q + loss =================
__global__ __launch_bounds__(256) void gather_kernel(const float* __restrict__ z,
                                                     const float* __restrict__ cb,
                                                     const int* __restrict__ idx_i,
                                                     float* __restrict__ out0,
                                                     float* __restrict__ accum) {
    int tid   = threadIdx.x;
    int blk   = blockIdx.x;
    int b     = blk >> 5;
    int chunk = (blk >> 3) & 3;
    int cgrp  = blk & 7;
    int hw = chunk * 256 + tid;
    int n  = b * 1024 + hw;
    int code = idx_i[n];
    const float* cp = cb + (size_t)code * CDIM + cgrp * 32;
    float lsum = 0.0f;
    size_t base = (size_t)b * 262144 + hw + (size_t)(cgrp * 32) * 1024;
#pragma unroll
    for (int cc = 0; cc < 8; ++cc) {
        float4 q4 = *(const float4*)(cp + cc * 4);
        float qv[4] = {q4.x, q4.y, q4.z, q4.w};
#pragma unroll
        for (int u = 0; u < 4; ++u) {
            size_t off = base + (size_t)(cc * 4 + u) * 1024;
            float zv = z[off];
            out0[off] = qv[u];
            float dfr = zv - qv[u];
            lsum = fmaf(dfr, dfr, lsum);
        }
    }
#pragma unroll
    for (int mm = 32; mm >= 1; mm >>= 1) lsum += __shfl_down(lsum, mm, 64);
    __shared__ float red[4];
    int wv = tid >> 6, ln = tid & 63;
    if (ln == 0) red[wv] = lsum;
    __syncthreads();
    if (tid == 0) atomicAdd(accum, (red[0] + red[1]) + (red[2] + red[3]));
}

__global__ void finalize_loss(const float* __restrict__ accum, float* __restrict__ out_loss) {
    out_loss[0] = accum[0] * (1.25f / 8388608.0f);
}

extern "C" void kernel_launch(void* const* d_in, const int* in_sizes, int n_in,
                              void* d_out, int out_size, void* d_ws, size_t ws_size,
                              hipStream_t stream) {
    const float* z  = (const float*)d_in[0];   // [32,256,32,32]
    const float* cb = (const float*)d_in[1];   // [1024,256]

    float* ws   = (float*)d_ws;
    float* esq  = ws + ESQ_OFF;
    float* zsqh = ws + ZSQH_OFF;
    float* tb   = ws + TB_OFF;
    float* ts   = ws + TS_OFF;
    int*   ti   = (int*)(ws + TI_OFF);
    int*   idx_i = (int*)(ws + IDX_OFF);
    int*   list = (int*)(ws + LIST_OFF);
    int*   cnt  = (int*)(ws + CNT_OFF);
    float* accum = ws + ACC_OFF;
    uint*  Bhi  = (uint*)(ws + BHI_OFF);
    uint*  Blo  = (uint*)(ws + BLO_OFF);
    float* cbT  = ws + TB_OFF;                 // reuses tb+ts region after finalize

    float* out0     = (float*)d_out;
    float* out_loss = out0 + ZQ_ELEMS;
    float* out_idxf = out0 + ZQ_ELEMS + 1;

    // A hi/lo fragments (32 MB) live in the z_q region of d_out (consumed before gather)
    uint* Ahi = (uint*)out0;
    uint* Alo = (uint*)(out0 + 4194304);

    hipMemsetAsync(cnt, 0, 8, stream);  // count + accum

    esq_kernel  <<<4,   256, 0, stream>>>(cb, esq);
    packB_kernel<<<128, 256, 0, stream>>>(cb, Bhi, Blo);
    packA_kernel<<<256, 256, 0, stream>>>(z, Ahi, Alo, zsqh);
    main_mfma   <<<512, 256, 0, stream>>>(Ahi, Alo, Bhi, Blo, esq, zsqh, tb, ts, ti);
    finalize_kernel<<<128, 256, 0, stream>>>(tb, ts, ti, out_idxf, idx_i, list, cnt);
    transpose_cb_kernel<<<1024, 256, 0, stream>>>(cb, cbT);
    rescan_kernel<<<512, 256, 0, stream>>>(z, cbT, esq, zsqh, list, cnt, out_idxf, idx_i);
    gather_kernel<<<1024, 256, 0, stream>>>(z, cb, idx_i, out0, accum);
    finalize_loss<<<1, 1, 0, stream>>>(accum, out_loss);
}